// Round 3
// baseline (328.785 us; speedup 1.0000x reference)
//
#include <hip/hip_runtime.h>
#include <hip/hip_bf16.h>
#include <cstdint>
#include <cstddef>

#define BATCH  4
#define SEQ    2048
#define EMBED  1024
#define NHEADS 16
#define HDIM   64

typedef __attribute__((ext_vector_type(8))) short  short8;   // 8 x bf16 (4 VGPRs)
typedef __attribute__((ext_vector_type(4))) float  floatx4;  // MFMA C/D

#define MASK_NEG (-1.0e30f)   // finite "minus infinity": no inf-inf NaN paths
#define LOG2E    1.44269504f

__device__ __forceinline__ float bf2f(ushort u) {
  union { uint32_t i; float f; } v; v.i = ((uint32_t)u) << 16; return v.f;
}
__device__ __forceinline__ ushort f2bf(float f) {
  union { float f; uint32_t i; } v; v.f = f;
  uint32_t u = v.i;
  return (ushort)((u + 0x7fffu + ((u >> 16) & 1u)) >> 16);   // RNE
}
// packed RNE f32x2 -> bf16x2 (v_cvt_pk_bf16_f32 on gfx950)
__device__ __forceinline__ uint32_t f2bf_pk(float a, float b) {
  union { __hip_bfloat162 h; uint32_t u; } v;
  v.h = __float22bfloat162_rn(make_float2(a, b));
  return v.u;
}
// raw v_exp_f32 (2^x): guaranteed single instruction, denorm-flush is fine
// (underflowed P terms contribute nothing).
__device__ __forceinline__ float fast_exp2(float x) {
  float r;
  asm("v_exp_f32 %0, %1" : "=v"(r) : "v"(x));
  return r;
}
__device__ __forceinline__ floatx4 max4(floatx4 a, floatx4 b) {
  floatx4 r;
  r[0] = fmaxf(a[0], b[0]); r[1] = fmaxf(a[1], b[1]);
  r[2] = fmaxf(a[2], b[2]); r[3] = fmaxf(a[3], b[3]);
  return r;
}
// async global->LDS 16B/lane; LDS dst must be wave-uniform base + lane*16
__device__ __forceinline__ void gll16(const ushort* g, ushort* l) {
  __builtin_amdgcn_global_load_lds(
      (const __attribute__((address_space(1))) void*)g,
      (__attribute__((address_space(3))) void*)l, 16, 0, 0);
}

// ---------------------------------------------------------------------------
// Dtype detection (flag=1 bf16-packed, 0 fp32). Verified working since round 3.
// ---------------------------------------------------------------------------
__global__ __launch_bounds__(256) void detect_dtype(
    const uint32_t* __restrict__ x, int* __restrict__ flag) {
  __shared__ int sh[256];
  int tid = threadIdx.x;
  int c = 0;
#pragma unroll
  for (int i = 0; i < 16; i++) {
    uint32_t w = x[tid * 16 + i];
    uint32_t lo = w & 0xFFFFu;
    int e = (int)((lo >> 7) & 0xFF);
    if (lo == 0u || (e >= 100 && e <= 140)) c++;
  }
  sh[tid] = c;
  __syncthreads();
  if (tid == 0) {
    int s = 0;
    for (int i = 0; i < 256; i++) s += sh[i];
    *flag = (s >= 3500) ? 1 : 0;
  }
}

// vectorized x conversion: 4 elems/thread/step
__global__ __launch_bounds__(256) void cvt_bf16_v4(
    const void* __restrict__ in, ushort* __restrict__ out,
    const int* __restrict__ flag, int n4) {
  bool isbf = (*flag != 0);
  int stride = gridDim.x * 256;
  for (int i = blockIdx.x * 256 + threadIdx.x; i < n4; i += stride) {
    if (isbf) {
      ((uint2*)out)[i] = ((const uint2*)in)[i];
    } else {
      float4 f = ((const float4*)in)[i];
      uint2 o;
      o.x = f2bf_pk(f.x, f.y);
      o.y = f2bf_pk(f.z, f.w);
      ((uint2*)out)[i] = o;
    }
  }
}

// both biases in one launch: i<3072 -> bqb, else bob
__global__ __launch_bounds__(256) void cvt_biases(
    const void* __restrict__ bq, const void* __restrict__ bo,
    ushort* __restrict__ bqb, ushort* __restrict__ bob,
    const int* __restrict__ flag) {
  bool isbf = (*flag != 0);
  int i = blockIdx.x * 256 + threadIdx.x;
  if (i < 3 * EMBED) {
    bqb[i] = isbf ? ((const ushort*)bq)[i] : f2bf(((const float*)bq)[i]);
  } else {
    int j = i - 3 * EMBED;
    bob[j] = isbf ? ((const ushort*)bo)[j] : f2bf(((const float*)bo)[j]);
  }
}

__global__ __launch_bounds__(256) void transpose_cvt(
    const void* __restrict__ in, ushort* __restrict__ out,
    const int* __restrict__ flag, int R, int C) {
  bool isbf = (*flag != 0);
  __shared__ ushort tile[32][33];
  int bx = blockIdx.x * 32;
  int by = blockIdx.y * 32;
  int tx = threadIdx.x & 31, ty = threadIdx.x >> 5;
#pragma unroll
  for (int i = 0; i < 32; i += 8) {
    size_t idx = (size_t)(by + ty + i) * C + bx + tx;
    tile[ty + i][tx] = isbf ? ((const ushort*)in)[idx] : f2bf(((const float*)in)[idx]);
  }
  __syncthreads();
#pragma unroll
  for (int i = 0; i < 32; i += 8)
    out[(size_t)(bx + ty + i) * R + by + tx] = tile[tx][ty + i];
}

// ---------------------------------------------------------------------------
// Batched transpose: V (BH, S, D) bf16 -> VT (BH, D, S) bf16.
// ---------------------------------------------------------------------------
__global__ __launch_bounds__(256) void transpose_v(
    const ushort* __restrict__ in, ushort* __restrict__ out) {
  __shared__ ushort tile[32][33];
  int bh = blockIdx.z;
  int s0 = blockIdx.x * 32;
  int d0 = blockIdx.y * 32;
  int tx = threadIdx.x & 31, ty = threadIdx.x >> 5;
  const ushort* ip = in + (size_t)bh * SEQ * HDIM;
  ushort* op = out + (size_t)bh * SEQ * HDIM;
#pragma unroll
  for (int i = 0; i < 32; i += 8)
    tile[ty + i][tx] = ip[(size_t)(s0 + ty + i) * HDIM + d0 + tx];
  __syncthreads();
#pragma unroll
  for (int i = 0; i < 32; i += 8)
    op[(size_t)(d0 + ty + i) * SEQ + s0 + tx] = tile[tx][ty + i];
}

// ---------------------------------------------------------------------------
// GEMM v3: BK=64, global_load_lds width-16 staging into XOR-chunk-swizzled
// LDS + XCD column-chunk swizzle (unchanged from round 2).
// ---------------------------------------------------------------------------
template <int EPI>
__global__ __launch_bounds__(256) void gemm128(
    const ushort* __restrict__ A, const ushort* __restrict__ BT,
    const ushort* __restrict__ bias,
    ushort* __restrict__ out0, ushort* __restrict__ out1, ushort* __restrict__ out2,
    const int* __restrict__ flag,
    int M, int N, int K) {
  __shared__ __align__(16) ushort Al[128 * 64];
  __shared__ __align__(16) ushort Bl[128 * 64];

  const int tid  = threadIdx.x;
  const int lane = tid & 63, wave = tid >> 6;
  const int quad = lane >> 4, l15 = lane & 15;
  const int wm = wave >> 1, wn = wave & 1;

  const int Lb  = blockIdx.y * gridDim.x + blockIdx.x;
  const int xcd = Lb & 7, ib = Lb >> 3;
  const int cpx = gridDim.x >> 3;          // gridDim.x % 8 == 0 for both uses
  const int bx  = xcd * cpx + (ib % cpx);
  const int by  = ib / cpx;
  const int rowA0 = by * 128;
  const int colB0 = bx * 128;

  floatx4 acc[4][4] = {};

  int srow[4], sc8[4];
#pragma unroll
  for (int j = 0; j < 4; j++) {
    int s = tid + j * 256;
    srow[j] = s >> 3;
    sc8[j] = ((s & 7) ^ (srow[j] & 7)) * 8;
  }

  for (int kk = 0; kk < K; kk += 64) {
    __syncthreads();
#pragma unroll
    for (int j = 0; j < 4; j++)
      gll16(&A[(size_t)(rowA0 + srow[j]) * K + kk + sc8[j]], &Al[(tid + j * 256) * 8]);
#pragma unroll
    for (int j = 0; j < 4; j++)
      gll16(&BT[(size_t)(colB0 + srow[j]) * K + kk + sc8[j]], &Bl[(tid + j * 256) * 8]);
    __syncthreads();

#pragma unroll
    for (int h = 0; h < 2; h++) {
      short8 af[4], bf[4];
#pragma unroll
      for (int mt = 0; mt < 4; mt++) {
        int row = wm * 64 + mt * 16 + l15;
        int pos = (quad + 4 * h) ^ (l15 & 7);
        af[mt] = *(const short8*)&Al[row * 64 + pos * 8];
      }
#pragma unroll
      for (int nt = 0; nt < 4; nt++) {
        int row = wn * 64 + nt * 16 + l15;
        int pos = (quad + 4 * h) ^ (l15 & 7);
        bf[nt] = *(const short8*)&Bl[row * 64 + pos * 8];
      }
#pragma unroll
      for (int mt = 0; mt < 4; mt++)
#pragma unroll
        for (int nt = 0; nt < 4; nt++)
          acc[mt][nt] = __builtin_amdgcn_mfma_f32_16x16x32_bf16(af[mt], bf[nt], acc[mt][nt], 0, 0, 0);
    }
  }

  const bool isbf = (EPI == 1) ? (*flag != 0) : true;

#pragma unroll
  for (int mt = 0; mt < 4; mt++)
#pragma unroll
    for (int nt = 0; nt < 4; nt++)
#pragma unroll
      for (int r = 0; r < 4; r++) {
        int row = rowA0 + wm * 64 + mt * 16 + quad * 4 + r;
        int col = colB0 + wn * 64 + nt * 16 + l15;
        float v = acc[mt][nt][r] + bf2f(bias[col]);
        if (EPI == 0) {
          int three = col >> 10, rem = col & 1023, h = rem >> 6, d = rem & 63;
          int b = row >> 11, s = row & 2047;
          ushort* dst = (three == 0) ? out0 : (three == 1) ? out1 : out2;
          dst[((size_t)(b * NHEADS + h) * SEQ + s) * HDIM + d] = f2bf(v);
        } else {
          if (isbf) out0[(size_t)row * N + col] = f2bf(v);
          else      ((float*)out0)[(size_t)row * N + col] = v;
        }
      }
}

// ---------------------------------------------------------------------------
// Flash attention v10: LDS-traffic diet. Round-2 counters: VALUBusy 50%,
// MfmaUtil 18%, HBM 12% -> nothing saturated except the (uncounted) DS pipe:
// ~26 b128-class LDS ops per 16-row wave-tile ~= 336 cyc/CU -> 74 us floor,
// matching the 84 us measured. Fix: 32 q-rows per wave (mf=2) so the same
// K/V fragment reads feed 2x the rows -> DS per 16-row unit halves (~168cy).
//  - 128-row q-tiles, 4 waves x 32 rows; grid 16 qt x 64 bh = 1024 blocks,
//    qt DESCENDING within each bh so big blocks dispatch first (backfill
//    smooths the causal imbalance; no diagonal pairing needed).
//  - LDS 49152 B (Kl 16K dbuf + Vt 16K dbuf + Pl 16K) -> 3 blocks/CU.
//  - diagonal: tile 2qt masked-for-all (mask is never-true for waves 2,3);
//    tile 2qt+1 only waves 2,3 (fully masked for waves 0,1 -> skipped).
//  - rest unchanged from v9: XOR swizzle, defer-max THR=8, fast_exp2,
//    quad-partial li, register-prefetch double buffer, 1 barrier/iter,
//    XCD remap (same L->bh grouping: 8 bh per XCD -> K/V L2-resident).
// ---------------------------------------------------------------------------
__global__ __launch_bounds__(256, 3) void attn_kernel(
    const ushort* __restrict__ Q, const ushort* __restrict__ K,
    const ushort* __restrict__ VT, ushort* __restrict__ Oout) {
  __shared__ __align__(16) ushort Kl[2][64 * 64];   // [key][d], swizzled
  __shared__ __align__(16) ushort Vt[2][64 * 64];   // [d][key], swizzled
  __shared__ __align__(16) ushort Pl[4][32 * 64];   // per-wave [qrow][key], swizzled

  const int tid  = threadIdx.x;
  const int lane = tid & 63, wave = tid >> 6;
  const int quad = lane >> 4, l15 = lane & 15;

  // XCD-aware remap: 1024 blocks; xcd = L%8 owns 8 consecutive bh (K/V fits
  // its L2); within a bh the 16 q-tiles run qt=15..0 (big first).
  const int L   = blockIdx.x + 16 * blockIdx.y + 256 * blockIdx.z;  // 0..1023
  const int xcd = L & 7;
  const int idx = L >> 3;                 // 0..127
  const int bh  = xcd * 8 + (idx >> 4);   // 0..63
  const int qt  = 15 - (idx & 15);        // 15..0 (descending dispatch)
  const int h   = bh & 15, b = bh >> 4;

  const ushort* Qp  = Q  + (size_t)bh * SEQ * HDIM;
  const ushort* Kp  = K  + (size_t)bh * SEQ * HDIM;
  const ushort* VTp = VT + (size_t)bh * SEQ * HDIM;  // [d][s]

  const float slope2 = exp2f(-0.5f * (float)(h + 1)) * LOG2E;
  const float c2 = 0.125f * LOG2E;

  // per-element ALiBi offsets within a tile: slope2 * (key - kb)
  floatx4 ab[4];
#pragma unroll
  for (int kct = 0; kct < 4; kct++)
#pragma unroll
    for (int r = 0; r < 4; r++)
      ab[kct][r] = slope2 * (float)(kct * 16 + quad * 4 + r);

  // staging: row = tid>>3 (and +32), source chunk sc = tid&7, LDS chunk
  // swizzled sc ^ (row&7). Row stride 64 elems = 128 B (16B-aligned rows).
  const int sr0 = tid >> 3, sr1 = sr0 + 32;
  const int sc  = tid & 7;
  const int so  = sc * 8;
  const int sw0 = sr0 * 64 + (sc ^ (sr0 & 7)) * 8;
  const int sw1 = sr1 * 64 + (sc ^ (sr0 & 7)) * 8;   // (sr1&7)==(sr0&7)
  const int sxr = l15 & 7;                            // read-side swizzle

  const int wq0 = qt * 128 + wave * 32;

  short8 qf[2][2];
#pragma unroll
  for (int mf = 0; mf < 2; mf++) {
    const ushort* qr = &Qp[(size_t)(wq0 + mf * 16 + l15) * HDIM];
    qf[mf][0] = *(const short8*)&qr[quad * 8];
    qf[mf][1] = *(const short8*)&qr[32 + quad * 8];
  }

  float m2s[2] = {MASK_NEG, MASK_NEG}, lis[2] = {0.f, 0.f};   // quad-partial li
  float qrowf[2];
#pragma unroll
  for (int mf = 0; mf < 2; mf++) qrowf[mf] = (float)(wq0 + mf * 16 + l15);
  floatx4 o_acc[2][4] = {};

// one K/V tile for BOTH mf halves (shared K/V fragment reads).
// MASKED is a literal 0/1 at every expansion site.
#define ATTN_TILE(KB, CUR, MASKED)                                            \
  do {                                                                        \
    short8 kfa[4], kfb[4];                                                    \
    _Pragma("unroll")                                                         \
    for (int kct = 0; kct < 4; kct++) {                                       \
      const ushort* kr = &Kl[CUR][(kct * 16 + l15) * 64];                     \
      kfa[kct] = *(const short8*)&kr[(quad ^ sxr) * 8];                       \
      kfb[kct] = *(const short8*)&kr[((quad + 4) ^ sxr) * 8];                 \
    }                                                                         \
    _Pragma("unroll")                                                         \
    for (int mf = 0; mf < 2; mf++) {                                          \
      floatx4 w[4];                                                           \
      _Pragma("unroll")                                                       \
      for (int kct = 0; kct < 4; kct++) {                                     \
        floatx4 z = {};                                                       \
        z = __builtin_amdgcn_mfma_f32_16x16x32_bf16(kfa[kct], qf[mf][0], z, 0, 0, 0); \
        z = __builtin_amdgcn_mfma_f32_16x16x32_bf16(kfb[kct], qf[mf][1], z, 0, 0, 0); \
        w[kct] = z * c2 + ab[kct];                                            \
      }                                                                       \
      if (MASKED) {                                                           \
        const float qrel = qrowf[mf] - (float)(KB);                           \
        _Pragma("unroll")                                                     \
        for (int kct = 0; kct < 4; kct++)                                     \
          _Pragma("unroll")                                                   \
          for (int r = 0; r < 4; r++)                                         \
            if ((float)(kct * 16 + quad * 4 + r) > qrel) w[kct][r] = MASK_NEG;\
      }                                                                       \
      floatx4 wm4 = max4(max4(w[0], w[1]), max4(w[2], w[3]));                 \
      float mloc = fmaxf(fmaxf(wm4[0], wm4[1]), fmaxf(wm4[2], wm4[3]));       \
      mloc = fmaxf(mloc, __shfl_xor(mloc, 16, 64));                           \
      mloc = fmaxf(mloc, __shfl_xor(mloc, 32, 64));                           \
      const float bk = slope2 * (float)(KB);                                  \
      const float mlt = mloc + bk;                                            \
      const unsigned long long g = __ballot(mlt > m2s[mf] + 8.0f);            \
      float al = 1.0f;                                                        \
      if (g) {                                                                \
        float mn = fmaxf(m2s[mf], mlt);                                       \
        al = fast_exp2(m2s[mf] - mn);                                         \
        m2s[mf] = mn;                                                         \
      }                                                                       \
      const float mnb = m2s[mf] - bk;                                         \
      float rs = 0.f;                                                         \
      _Pragma("unroll")                                                       \
      for (int kct = 0; kct < 4; kct++) {                                     \
        float p0 = fast_exp2(w[kct][0] - mnb);                                \
        float p1 = fast_exp2(w[kct][1] - mnb);                                \
        float p2 = fast_exp2(w[kct][2] - mnb);                                \
        float p3 = fast_exp2(w[kct][3] - mnb);                                \
        rs += (p0 + p1) + (p2 + p3);                                          \
        uint2 pw;                                                             \
        pw.x = f2bf_pk(p0, p1);                                               \
        pw.y = f2bf_pk(p2, p3);                                               \
        *(uint2*)&Pl[wave][(mf * 16 + l15) * 64 +                             \
                           ((kct * 2 + (quad >> 1)) ^ sxr) * 8 +              \
                           (quad & 1) * 4] = pw;                              \
      }                                                                       \
      if (g) {                                                                \
        floatx4 alrv;                                                         \
        _Pragma("unroll")                                                     \
        for (int r = 0; r < 4; r++) alrv[r] = __shfl(al, quad * 4 + r, 16);   \
        _Pragma("unroll")                                                     \
        for (int ct = 0; ct < 4; ct++) o_acc[mf][ct] *= alrv;                 \
        lis[mf] = lis[mf] * al + rs;                                          \
      } else {                                                                \
        lis[mf] += rs;                                                        \
      }                                                                       \
    }                                                                         \
    _Pragma("unroll")                                                         \
    for (int ks = 0; ks < 2; ks++) {                                          \
      short8 vf[4];                                                           \
      _Pragma("unroll")                                                       \
      for (int ct = 0; ct < 4; ct++)                                          \
        vf[ct] = *(const short8*)&Vt[CUR][(ct * 16 + l15) * 64 +              \
                                          ((ks * 4 + quad) ^ sxr) * 8];       \
      _Pragma("unroll")                                                       \
      for (int mf = 0; mf < 2; mf++) {                                        \
        short8 pf = *(const short8*)&Pl[wave][(mf * 16 + l15) * 64 +          \
                                              ((ks * 4 + quad) ^ sxr) * 8];   \
        _Pragma("unroll")                                                     \
        for (int ct = 0; ct < 4; ct++)                                        \
          o_acc[mf][ct] = __builtin_amdgcn_mfma_f32_16x16x32_bf16(            \
              pf, vf[ct], o_acc[mf][ct], 0, 0, 0);                            \
      }                                                                       \
    }                                                                         \
  } while (0)

  // stage tile 0 -> buffer 0 (block start: no prior readers, no pre-barrier)
  uint4 pk0 = *(const uint4*)&Kp[(size_t)sr0 * HDIM + so];
  uint4 pk1 = *(const uint4*)&Kp[(size_t)sr1 * HDIM + so];
  uint4 pv0 = *(const uint4*)&VTp[(size_t)sr0 * SEQ + so];
  uint4 pv1 = *(const uint4*)&VTp[(size_t)sr1 * SEQ + so];
  *(uint4*)&Kl[0][sw0] = pk0;
  *(uint4*)&Kl[0][sw1] = pk1;
  *(uint4*)&Vt[0][sw0] = pv0;
  *(uint4*)&Vt[0][sw1] = pv1;
  __syncthreads();

  // tiles 0 .. 2qt+1; tiles < 2qt are unmasked for all waves
  const int nfull = 2 * qt;
  for (int kt = 0; kt < nfull; kt++) {
    const int kb = kt * 64;
    const int cur = kt & 1;

    {  // prefetch tile kt+1 into registers
      const int kb2 = kb + 64;
      pk0 = *(const uint4*)&Kp[(size_t)(kb2 + sr0) * HDIM + so];
      pk1 = *(const uint4*)&Kp[(size_t)(kb2 + sr1) * HDIM + so];
      pv0 = *(const uint4*)&VTp[(size_t)sr0 * SEQ + kb2 + so];
      pv1 = *(const uint4*)&VTp[(size_t)sr1 * SEQ + kb2 + so];
    }

    ATTN_TILE(kb, cur, 0);

    {  // drain prefetch into the other buffer (its readers left last iter)
      const int nxt = cur ^ 1;
      *(uint4*)&Kl[nxt][sw0] = pk0;
      *(uint4*)&Kl[nxt][sw1] = pk1;
      *(uint4*)&Vt[nxt][sw0] = pv0;
      *(uint4*)&Vt[nxt][sw1] = pv1;
    }
    __syncthreads();
  }

  // tile 2qt: diagonal for waves 0,1; mask condition is never-true for
  // waves 2,3 (16 harmless cndmasks). Prefetch tile 2qt+1 for waves 2,3.
  {
    const int kb = nfull * 64;
    const int cur = nfull & 1;
    const int kb2 = kb + 64;
    pk0 = *(const uint4*)&Kp[(size_t)(kb2 + sr0) * HDIM + so];
    pk1 = *(const uint4*)&Kp[(size_t)(kb2 + sr1) * HDIM + so];
    pv0 = *(const uint4*)&VTp[(size_t)sr0 * SEQ + kb2 + so];
    pv1 = *(const uint4*)&VTp[(size_t)sr1 * SEQ + kb2 + so];

    ATTN_TILE(kb, cur, 1);

    const int nxt = cur ^ 1;
    *(uint4*)&Kl[nxt][sw0] = pk0;
    *(uint4*)&Kl[nxt][sw1] = pk1;
    *(uint4*)&Vt[nxt][sw0] = pv0;
    *(uint4*)&Vt[nxt][sw1] = pv1;
    __syncthreads();
  }

  // tile 2qt+1: diagonal for waves 2,3; fully masked (zero) for waves 0,1.
  // No trailing barrier needed (kernel ends; per-wave state only).
  if (wave & 2) {
    ATTN_TILE((nfull + 1) * 64, (nfull + 1) & 1, 1);
  }

  // epilogue: O rows q = wq0+mf*16+quad*4+r, cols d = ct*16+l15
#pragma unroll
  for (int mf = 0; mf < 2; mf++) {
    float lif = lis[mf] + __shfl_xor(lis[mf], 16, 64);
    lif += __shfl_xor(lif, 32, 64);
    float inv = 1.0f / fmaxf(lif, 1e-20f);
    float invr[4];
#pragma unroll
    for (int r = 0; r < 4; r++) invr[r] = __shfl(inv, quad * 4 + r, 16);
#pragma unroll
    for (int ct = 0; ct < 4; ct++)
#pragma unroll
      for (int r = 0; r < 4; r++) {
        int q = wq0 + mf * 16 + quad * 4 + r;
        float v = o_acc[mf][ct][r] * invr[r];
        Oout[(size_t)(b * SEQ + q) * EMBED + h * HDIM + ct * 16 + l15] = f2bf(v);
      }
  }
#undef ATTN_TILE
}

// ---------------------------------------------------------------------------
// ws layout (bytes):
//   flag @ 0          (1024)
//   xb   @ 1024       16777216
//   WTq  @ 16778240    6291456
//   WTo  @ 23069696    2097152
//   bqb  @ 25166848       6144
//   bob  @ 25172992       2048
//   Kw   @ 25175040   16777216
//   Vw   @ 41952256   16777216   (dead after transpose_v -> reused as Aw)
//   VT   @ 58729472   16777216   -> end 75506688
//   Qw   @ 75506688 if ws fits, else Q lives in d_out.
// ---------------------------------------------------------------------------
extern "C" void kernel_launch(void* const* d_in, const int* in_sizes, int n_in,
                              void* d_out, int out_size, void* d_ws, size_t ws_size,
                              hipStream_t stream) {
  const void* x     = d_in[0];
  const void* W_qkv = d_in[2];
  const void* b_qkv = d_in[3];
  const void* W_out = d_in[4];
  const void* b_out = d_in[5];

  char* ws = (char*)d_ws;
  int*    flag = (int*)(ws + 0);
  ushort* xb   = (ushort*)(ws + 1024);
  ushort* WTq  = (ushort*)(ws + 16778240);
  ushort* WTo  = (ushort*)(ws + 23069696);
  ushort* bqb  = (ushort*)(ws + 25166848);
  ushort* bob  = (ushort*)(ws + 25172992);
  ushort* Kw   = (ushort*)(ws + 25175040);
  ushort* Vw   = (ushort*)(ws + 41952256);
  ushort* VTw  = (ushort*)(ws + 58729472);
  ushort* Aw   = Vw;   // Vw dead after transpose_v
  ushort* Qw   = (ws_size >= (size_t)75506688 + 16777216)
                   ? (ushort*)(ws + 75506688)
                   : (ushort*)d_out;   // d_out as scratch: dead until final GEMM

  detect_dtype<<<1, 256, 0, stream>>>((const uint32_t*)x, flag);

  cvt_bf16_v4<<<2048, 256, 0, stream>>>(x, xb, flag, BATCH * SEQ * EMBED / 4);
  cvt_biases<<<16, 256, 0, stream>>>(b_qkv, b_out, bqb, bob, flag);

  transpose_cvt<<<dim3(3072 / 32, 1024 / 32), 256, 0, stream>>>(W_qkv, WTq, flag, 1024, 3072);
  transpose_cvt<<<dim3(1024 / 32, 1024 / 32), 256, 0, stream>>>(W_out, WTo, flag, 1024, 1024);

  gemm128<0><<<dim3(3072 / 128, 8192 / 128), 256, 0, stream>>>(
      xb, WTq, bqb, Qw, Kw, Vw, flag, BATCH * SEQ, 3 * EMBED, EMBED);

  transpose_v<<<dim3(SEQ / 32, HDIM / 32, BATCH * NHEADS), 256, 0, stream>>>(Vw, VTw);

  attn_kernel<<<dim3(16, 16, 4), 256, 0, stream>>>(Qw, Kw, VTw, Aw);

  gemm128<1><<<dim3(1024 / 128, 8192 / 128), 256, 0, stream>>>(
      Aw, WTo, bob, (ushort*)d_out, nullptr, nullptr, flag, BATCH * SEQ, EMBED, EMBED);
}

// Round 4
// 294.988 us; speedup vs baseline: 1.1146x; 1.1146x over previous
//
#include <hip/hip_runtime.h>
#include <hip/hip_bf16.h>
#include <cstdint>
#include <cstddef>

#define BATCH  4
#define SEQ    2048
#define EMBED  1024
#define NHEADS 16
#define HDIM   64

typedef __attribute__((ext_vector_type(8))) short  short8;   // 8 x bf16 (4 VGPRs)
typedef __attribute__((ext_vector_type(4))) float  floatx4;  // MFMA C/D

#define MASK_NEG (-1.0e30f)   // finite "minus infinity": no inf-inf NaN paths
#define LOG2E    1.44269504f

__device__ __forceinline__ float bf2f(ushort u) {
  union { uint32_t i; float f; } v; v.i = ((uint32_t)u) << 16; return v.f;
}
__device__ __forceinline__ ushort f2bf(float f) {
  union { float f; uint32_t i; } v; v.f = f;
  uint32_t u = v.i;
  return (ushort)((u + 0x7fffu + ((u >> 16) & 1u)) >> 16);   // RNE
}
// packed RNE f32x2 -> bf16x2 (v_cvt_pk_bf16_f32 on gfx950)
__device__ __forceinline__ uint32_t f2bf_pk(float a, float b) {
  union { __hip_bfloat162 h; uint32_t u; } v;
  v.h = __float22bfloat162_rn(make_float2(a, b));
  return v.u;
}
// raw v_exp_f32 (2^x): guaranteed single instruction, denorm-flush is fine
// (underflowed P terms contribute nothing).
__device__ __forceinline__ float fast_exp2(float x) {
  float r;
  asm("v_exp_f32 %0, %1" : "=v"(r) : "v"(x));
  return r;
}
__device__ __forceinline__ floatx4 max4(floatx4 a, floatx4 b) {
  floatx4 r;
  r[0] = fmaxf(a[0], b[0]); r[1] = fmaxf(a[1], b[1]);
  r[2] = fmaxf(a[2], b[2]); r[3] = fmaxf(a[3], b[3]);
  return r;
}
// async global->LDS 16B/lane; LDS dst must be wave-uniform base + lane*16
__device__ __forceinline__ void gll16(const ushort* g, ushort* l) {
  __builtin_amdgcn_global_load_lds(
      (const __attribute__((address_space(1))) void*)g,
      (__attribute__((address_space(3))) void*)l, 16, 0, 0);
}

// ---------------------------------------------------------------------------
// Dtype detection (flag=1 bf16-packed, 0 fp32). Verified working since round 3.
// ---------------------------------------------------------------------------
__global__ __launch_bounds__(256) void detect_dtype(
    const uint32_t* __restrict__ x, int* __restrict__ flag) {
  __shared__ int sh[256];
  int tid = threadIdx.x;
  int c = 0;
#pragma unroll
  for (int i = 0; i < 16; i++) {
    uint32_t w = x[tid * 16 + i];
    uint32_t lo = w & 0xFFFFu;
    int e = (int)((lo >> 7) & 0xFF);
    if (lo == 0u || (e >= 100 && e <= 140)) c++;
  }
  sh[tid] = c;
  __syncthreads();
  if (tid == 0) {
    int s = 0;
    for (int i = 0; i < 256; i++) s += sh[i];
    *flag = (s >= 3500) ? 1 : 0;
  }
}

// vectorized x conversion: 4 elems/thread/step
__global__ __launch_bounds__(256) void cvt_bf16_v4(
    const void* __restrict__ in, ushort* __restrict__ out,
    const int* __restrict__ flag, int n4) {
  bool isbf = (*flag != 0);
  int stride = gridDim.x * 256;
  for (int i = blockIdx.x * 256 + threadIdx.x; i < n4; i += stride) {
    if (isbf) {
      ((uint2*)out)[i] = ((const uint2*)in)[i];
    } else {
      float4 f = ((const float4*)in)[i];
      uint2 o;
      o.x = f2bf_pk(f.x, f.y);
      o.y = f2bf_pk(f.z, f.w);
      ((uint2*)out)[i] = o;
    }
  }
}

// both biases in one launch: i<3072 -> bqb, else bob
__global__ __launch_bounds__(256) void cvt_biases(
    const void* __restrict__ bq, const void* __restrict__ bo,
    ushort* __restrict__ bqb, ushort* __restrict__ bob,
    const int* __restrict__ flag) {
  bool isbf = (*flag != 0);
  int i = blockIdx.x * 256 + threadIdx.x;
  if (i < 3 * EMBED) {
    bqb[i] = isbf ? ((const ushort*)bq)[i] : f2bf(((const float*)bq)[i]);
  } else {
    int j = i - 3 * EMBED;
    bob[j] = isbf ? ((const ushort*)bo)[j] : f2bf(((const float*)bo)[j]);
  }
}

__global__ __launch_bounds__(256) void transpose_cvt(
    const void* __restrict__ in, ushort* __restrict__ out,
    const int* __restrict__ flag, int R, int C) {
  bool isbf = (*flag != 0);
  __shared__ ushort tile[32][33];
  int bx = blockIdx.x * 32;
  int by = blockIdx.y * 32;
  int tx = threadIdx.x & 31, ty = threadIdx.x >> 5;
#pragma unroll
  for (int i = 0; i < 32; i += 8) {
    size_t idx = (size_t)(by + ty + i) * C + bx + tx;
    tile[ty + i][tx] = isbf ? ((const ushort*)in)[idx] : f2bf(((const float*)in)[idx]);
  }
  __syncthreads();
#pragma unroll
  for (int i = 0; i < 32; i += 8)
    out[(size_t)(bx + ty + i) * R + by + tx] = tile[tx][ty + i];
}

// ---------------------------------------------------------------------------
// Batched transpose: V (BH, S, D) bf16 -> VT (BH, D, S) bf16.
// ---------------------------------------------------------------------------
__global__ __launch_bounds__(256) void transpose_v(
    const ushort* __restrict__ in, ushort* __restrict__ out) {
  __shared__ ushort tile[32][33];
  int bh = blockIdx.z;
  int s0 = blockIdx.x * 32;
  int d0 = blockIdx.y * 32;
  int tx = threadIdx.x & 31, ty = threadIdx.x >> 5;
  const ushort* ip = in + (size_t)bh * SEQ * HDIM;
  ushort* op = out + (size_t)bh * SEQ * HDIM;
#pragma unroll
  for (int i = 0; i < 32; i += 8)
    tile[ty + i][tx] = ip[(size_t)(s0 + ty + i) * HDIM + d0 + tx];
  __syncthreads();
#pragma unroll
  for (int i = 0; i < 32; i += 8)
    op[(size_t)(d0 + ty + i) * SEQ + s0 + tx] = tile[tx][ty + i];
}

// ---------------------------------------------------------------------------
// GEMM v2 (reverted to round-1 block mapping): the round-2 XCD column-chunk
// remap cost ~12 us on the non-attn total (others 205/206 -> 223/213 us);
// plain ascending blockIdx keeps consecutive blocks on the same A row-panel
// (natural L2/L3 sharing). BK=64, global_load_lds width-16 staging into
// XOR-chunk-swizzled unpadded LDS.
// ---------------------------------------------------------------------------
template <int EPI>
__global__ __launch_bounds__(256) void gemm128(
    const ushort* __restrict__ A, const ushort* __restrict__ BT,
    const ushort* __restrict__ bias,
    ushort* __restrict__ out0, ushort* __restrict__ out1, ushort* __restrict__ out2,
    const int* __restrict__ flag,
    int M, int N, int K) {
  __shared__ __align__(16) ushort Al[128 * 64];
  __shared__ __align__(16) ushort Bl[128 * 64];

  const int tid  = threadIdx.x;
  const int lane = tid & 63, wave = tid >> 6;
  const int quad = lane >> 4, l15 = lane & 15;
  const int wm = wave >> 1, wn = wave & 1;
  const int rowA0 = blockIdx.y * 128;
  const int colB0 = blockIdx.x * 128;

  floatx4 acc[4][4] = {};

  int srow[4], sc8[4];
#pragma unroll
  for (int j = 0; j < 4; j++) {
    int s = tid + j * 256;
    srow[j] = s >> 3;
    sc8[j] = ((s & 7) ^ (srow[j] & 7)) * 8;
  }

  for (int kk = 0; kk < K; kk += 64) {
    __syncthreads();
#pragma unroll
    for (int j = 0; j < 4; j++)
      gll16(&A[(size_t)(rowA0 + srow[j]) * K + kk + sc8[j]], &Al[(tid + j * 256) * 8]);
#pragma unroll
    for (int j = 0; j < 4; j++)
      gll16(&BT[(size_t)(colB0 + srow[j]) * K + kk + sc8[j]], &Bl[(tid + j * 256) * 8]);
    __syncthreads();

#pragma unroll
    for (int h = 0; h < 2; h++) {
      short8 af[4], bf[4];
#pragma unroll
      for (int mt = 0; mt < 4; mt++) {
        int row = wm * 64 + mt * 16 + l15;
        int pos = (quad + 4 * h) ^ (l15 & 7);
        af[mt] = *(const short8*)&Al[row * 64 + pos * 8];
      }
#pragma unroll
      for (int nt = 0; nt < 4; nt++) {
        int row = wn * 64 + nt * 16 + l15;
        int pos = (quad + 4 * h) ^ (l15 & 7);
        bf[nt] = *(const short8*)&Bl[row * 64 + pos * 8];
      }
#pragma unroll
      for (int mt = 0; mt < 4; mt++)
#pragma unroll
        for (int nt = 0; nt < 4; nt++)
          acc[mt][nt] = __builtin_amdgcn_mfma_f32_16x16x32_bf16(af[mt], bf[nt], acc[mt][nt], 0, 0, 0);
    }
  }

  const bool isbf = (EPI == 1) ? (*flag != 0) : true;

#pragma unroll
  for (int mt = 0; mt < 4; mt++)
#pragma unroll
    for (int nt = 0; nt < 4; nt++)
#pragma unroll
      for (int r = 0; r < 4; r++) {
        int row = rowA0 + wm * 64 + mt * 16 + quad * 4 + r;
        int col = colB0 + wn * 64 + nt * 16 + l15;
        float v = acc[mt][nt][r] + bf2f(bias[col]);
        if (EPI == 0) {
          int three = col >> 10, rem = col & 1023, h = rem >> 6, d = rem & 63;
          int b = row >> 11, s = row & 2047;
          ushort* dst = (three == 0) ? out0 : (three == 1) ? out1 : out2;
          dst[((size_t)(b * NHEADS + h) * SEQ + s) * HDIM + d] = f2bf(v);
        } else {
          if (isbf) out0[(size_t)row * N + col] = f2bf(v);
          else      ((float*)out0)[(size_t)row * N + col] = v;
        }
      }
}

// ---------------------------------------------------------------------------
// Flash attention v11: v9 structure (round 2, 84 us: 64-row q-tiles,
// 16 rows/wave, diagonal pairing qt<->31-qt, 4 blocks/CU) restored after
// v10's load-imbalance regression (uniform block duration is load-bearing).
// New: K/V staging via global_load_lds DMA (was reg round-trip + ds_write):
//  - removes 4 b128 ds_writes/wave-tile from the DS pipe (288->240 cyc,
//    the measured bottleneck: DS floor ~63 us of 84 measured)
//  - frees the 16 prefetch VGPRs
//  - swizzle preserved by pre-swizzling the global SOURCE chunk
//    (c = pos ^ (row&7), the gemm pattern); LDS dest stays linear as the
//    DMA requires. Issue-before-compute keeps the async overlap; the
//    compiler's vmcnt drain at __syncthreads covers completion.
// Rest unchanged: XOR swizzle reads, defer-max THR=8, fast_exp2,
// quad-partial li, peeled masked diagonal, 1 barrier/iter, XCD bh-grouping.
// ---------------------------------------------------------------------------
__global__ __launch_bounds__(256, 4) void attn_kernel(
    const ushort* __restrict__ Q, const ushort* __restrict__ K,
    const ushort* __restrict__ VT, ushort* __restrict__ Oout) {
  __shared__ __align__(16) ushort Kl[2][64 * 64];   // [key][d], swizzled
  __shared__ __align__(16) ushort Vt[2][64 * 64];   // [d][key], swizzled
  __shared__ __align__(16) ushort Pl[4][16 * 64];   // per-wave [qrow][key], swizzled

  const int tid  = threadIdx.x;
  const int lane = tid & 63, wave = tid >> 6;
  const int quad = lane >> 4, l15 = lane & 15;

  // XCD-aware remap: blocks L with L%8==xcd form one XCD's resident set;
  // give each xcd 8 whole (b,h) groups so K/V (8 x 512KB) fits its L2.
  const int L   = blockIdx.x + 16 * blockIdx.y + 256 * blockIdx.z;  // 0..1023
  const int xcd = L & 7;
  const int idx = L >> 3;                 // 0..127
  const int bh  = xcd * 8 + (idx >> 4);   // 0..63
  const int p   = idx & 15;               // diagonal pair index
  const int h   = bh & 15, b = bh >> 4;

  const ushort* Qp  = Q  + (size_t)bh * SEQ * HDIM;
  const ushort* Kp  = K  + (size_t)bh * SEQ * HDIM;
  const ushort* VTp = VT + (size_t)bh * SEQ * HDIM;  // [d][s]

  const float slope2 = exp2f(-0.5f * (float)(h + 1)) * LOG2E;
  const float c2 = 0.125f * LOG2E;

  // per-element ALiBi offsets within a tile: slope2 * (key - kb)
  floatx4 ab[4];
#pragma unroll
  for (int kct = 0; kct < 4; kct++)
#pragma unroll
    for (int r = 0; r < 4; r++)
      ab[kct][r] = slope2 * (float)(kct * 16 + quad * 4 + r);

  // DMA staging: thread covers (row = tid>>3, pos = tid&7) and (row+32, pos).
  // LDS dest linear: elem tid*8 (+2048 for second half). Source chunk
  // pre-swizzled: c = pos ^ (row&7); (row+32)&7 == row&7.
  const int sr0 = tid >> 3;
  const int scc = ((tid & 7) ^ (sr0 & 7)) * 8;        // source elem offset
  const int sxr = l15 & 7;                            // read-side swizzle

#define STAGE(KB, BUF)                                                        \
  do {                                                                        \
    gll16(&Kp[(size_t)((KB) + sr0) * HDIM + scc],       &Kl[BUF][tid * 8]);   \
    gll16(&Kp[(size_t)((KB) + sr0 + 32) * HDIM + scc],  &Kl[BUF][tid * 8 + 2048]); \
    gll16(&VTp[(size_t)sr0 * SEQ + (KB) + scc],         &Vt[BUF][tid * 8]);   \
    gll16(&VTp[(size_t)(sr0 + 32) * SEQ + (KB) + scc],  &Vt[BUF][tid * 8 + 2048]); \
  } while (0)

// one K/V tile: QK^T -> (optional mask) -> online softmax -> PV.
// MASKED is a literal 0/1 at every expansion site.
#define ATTN_TILE(KB, CUR, MASKED)                                            \
  do {                                                                        \
    floatx4 w[4];                                                             \
    _Pragma("unroll")                                                         \
    for (int kct = 0; kct < 4; kct++) {                                       \
      const ushort* kr = &Kl[CUR][(kct * 16 + l15) * 64];                     \
      short8 a0 = *(const short8*)&kr[(quad ^ sxr) * 8];                      \
      short8 a1 = *(const short8*)&kr[((quad + 4) ^ sxr) * 8];                \
      floatx4 z = {};                                                         \
      z = __builtin_amdgcn_mfma_f32_16x16x32_bf16(a0, qf0, z, 0, 0, 0);       \
      z = __builtin_amdgcn_mfma_f32_16x16x32_bf16(a1, qf1, z, 0, 0, 0);       \
      w[kct] = z * c2 + ab[kct];                                              \
    }                                                                         \
    if (MASKED) {                                                             \
      const float qrel = qrowf - (float)(KB);                                 \
      _Pragma("unroll")                                                       \
      for (int kct = 0; kct < 4; kct++)                                       \
        _Pragma("unroll")                                                     \
        for (int r = 0; r < 4; r++)                                           \
          if ((float)(kct * 16 + quad * 4 + r) > qrel) w[kct][r] = MASK_NEG;  \
    }                                                                         \
    floatx4 wm4 = max4(max4(w[0], w[1]), max4(w[2], w[3]));                   \
    float mloc = fmaxf(fmaxf(wm4[0], wm4[1]), fmaxf(wm4[2], wm4[3]));         \
    mloc = fmaxf(mloc, __shfl_xor(mloc, 16, 64));                             \
    mloc = fmaxf(mloc, __shfl_xor(mloc, 32, 64));                             \
    const float bk = slope2 * (float)(KB);                                    \
    const float mlt = mloc + bk;                                              \
    const unsigned long long g = __ballot(mlt > m2 + 8.0f);                   \
    float al = 1.0f;                                                          \
    if (g) {                                                                  \
      float mn = fmaxf(m2, mlt);                                              \
      al = fast_exp2(m2 - mn);                                                \
      m2 = mn;                                                                \
    }                                                                         \
    const float mnb = m2 - bk;                                                \
    float rs = 0.f;                                                           \
    _Pragma("unroll")                                                         \
    for (int kct = 0; kct < 4; kct++) {                                       \
      float p0 = fast_exp2(w[kct][0] - mnb);                                  \
      float p1 = fast_exp2(w[kct][1] - mnb);                                  \
      float p2 = fast_exp2(w[kct][2] - mnb);                                  \
      float p3 = fast_exp2(w[kct][3] - mnb);                                  \
      rs += (p0 + p1) + (p2 + p3);                                            \
      uint2 pw;                                                               \
      pw.x = f2bf_pk(p0, p1);                                                 \
      pw.y = f2bf_pk(p2, p3);                                                 \
      *(uint2*)&Pl[wave][l15 * 64 + ((kct * 2 + (quad >> 1)) ^ sxr) * 8 +     \
                         (quad & 1) * 4] = pw;                                \
    }                                                                         \
    if (g) {                                                                  \
      floatx4 alrv;                                                           \
      _Pragma("unroll")                                                       \
      for (int r = 0; r < 4; r++) alrv[r] = __shfl(al, quad * 4 + r, 16);     \
      _Pragma("unroll")                                                       \
      for (int ct = 0; ct < 4; ct++) o_acc[ct] *= alrv;                       \
      li = li * al + rs;                                                      \
    } else {                                                                  \
      li += rs;                                                               \
    }                                                                         \
    _Pragma("unroll")                                                         \
    for (int ks = 0; ks < 2; ks++) {                                          \
      short8 vf[4];                                                           \
      _Pragma("unroll")                                                       \
      for (int ct = 0; ct < 4; ct++)                                          \
        vf[ct] = *(const short8*)&Vt[CUR][(ct * 16 + l15) * 64 +              \
                                          ((ks * 4 + quad) ^ sxr) * 8];       \
      short8 pf = *(const short8*)&Pl[wave][l15 * 64 +                        \
                                            ((ks * 4 + quad) ^ sxr) * 8];     \
      _Pragma("unroll")                                                       \
      for (int ct = 0; ct < 4; ct++)                                          \
        o_acc[ct] = __builtin_amdgcn_mfma_f32_16x16x32_bf16(pf, vf[ct],       \
                                                            o_acc[ct], 0, 0, 0); \
    }                                                                         \
  } while (0)

  for (int qsel = 0; qsel < 2; qsel++) {
    const int qt  = qsel ? (31 - p) : p;      // 0..31
    const int wq0 = qt * 64 + wave * 16;

    short8 qf0, qf1;
    {
      const ushort* qr = &Qp[(size_t)(wq0 + l15) * HDIM];
      qf0 = *(const short8*)&qr[quad * 8];
      qf1 = *(const short8*)&qr[32 + quad * 8];
    }

    float m2 = MASK_NEG, li = 0.f;            // li is quad-partial
    const float qrowf = (float)(wq0 + l15);
    floatx4 o_acc[4] = {};

    // prologue: barrier (prev qsel's readers of buf0), then DMA tile 0
    __syncthreads();
    STAGE(0, 0);
    __syncthreads();   // drains own vmcnt, then barrier -> buf0 ready

    const int last = qt;   // tiles 0..last; only tile `last` needs the mask
    for (int kt = 0; kt < last; kt++) {
      const int cur = kt & 1;
      STAGE((kt + 1) * 64, cur ^ 1);   // async DMA next tile (its readers left last iter)
      ATTN_TILE(kt * 64, cur, 0);
      __syncthreads();                 // drain DMA + make it visible
    }

    // peeled diagonal tile (no prefetch, no trailing barrier: the next
    // qsel's pre-stage barrier covers the buffer reuse)
    ATTN_TILE(last * 64, last & 1, 1);

    // epilogue: O rows q = wq0+quad*4+r, cols d = ct*16+l15
    {
      float lif = li + __shfl_xor(li, 16, 64);
      lif += __shfl_xor(lif, 32, 64);
      float inv = 1.0f / fmaxf(lif, 1e-20f);
      float invr[4];
#pragma unroll
      for (int r = 0; r < 4; r++) invr[r] = __shfl(inv, quad * 4 + r, 16);
#pragma unroll
      for (int ct = 0; ct < 4; ct++)
#pragma unroll
        for (int r = 0; r < 4; r++) {
          int q = wq0 + quad * 4 + r;
          float v = o_acc[ct][r] * invr[r];
          Oout[(size_t)(b * SEQ + q) * EMBED + h * HDIM + ct * 16 + l15] = f2bf(v);
        }
    }
  }
#undef ATTN_TILE
#undef STAGE
}

// ---------------------------------------------------------------------------
// ws layout (bytes):
//   flag @ 0          (1024)
//   xb   @ 1024       16777216
//   WTq  @ 16778240    6291456
//   WTo  @ 23069696    2097152
//   bqb  @ 25166848       6144
//   bob  @ 25172992       2048
//   Kw   @ 25175040   16777216
//   Vw   @ 41952256   16777216   (dead after transpose_v -> reused as Aw)
//   VT   @ 58729472   16777216   -> end 75506688
//   Qw   @ 75506688 if ws fits, else Q lives in d_out.
// ---------------------------------------------------------------------------
extern "C" void kernel_launch(void* const* d_in, const int* in_sizes, int n_in,
                              void* d_out, int out_size, void* d_ws, size_t ws_size,
                              hipStream_t stream) {
  const void* x     = d_in[0];
  const void* W_qkv = d_in[2];
  const void* b_qkv = d_in[3];
  const void* W_out = d_in[4];
  const void* b_out = d_in[5];

  char* ws = (char*)d_ws;
  int*    flag = (int*)(ws + 0);
  ushort* xb   = (ushort*)(ws + 1024);
  ushort* WTq  = (ushort*)(ws + 16778240);
  ushort* WTo  = (ushort*)(ws + 23069696);
  ushort* bqb  = (ushort*)(ws + 25166848);
  ushort* bob  = (ushort*)(ws + 25172992);
  ushort* Kw   = (ushort*)(ws + 25175040);
  ushort* Vw   = (ushort*)(ws + 41952256);
  ushort* VTw  = (ushort*)(ws + 58729472);
  ushort* Aw   = Vw;   // Vw dead after transpose_v
  ushort* Qw   = (ws_size >= (size_t)75506688 + 16777216)
                   ? (ushort*)(ws + 75506688)
                   : (ushort*)d_out;   // d_out as scratch: dead until final GEMM

  detect_dtype<<<1, 256, 0, stream>>>((const uint32_t*)x, flag);

  cvt_bf16_v4<<<2048, 256, 0, stream>>>(x, xb, flag, BATCH * SEQ * EMBED / 4);
  cvt_biases<<<16, 256, 0, stream>>>(b_qkv, b_out, bqb, bob, flag);

  transpose_cvt<<<dim3(3072 / 32, 1024 / 32), 256, 0, stream>>>(W_qkv, WTq, flag, 1024, 3072);
  transpose_cvt<<<dim3(1024 / 32, 1024 / 32), 256, 0, stream>>>(W_out, WTo, flag, 1024, 1024);

  gemm128<0><<<dim3(3072 / 128, 8192 / 128), 256, 0, stream>>>(
      xb, WTq, bqb, Qw, Kw, Vw, flag, BATCH * SEQ, 3 * EMBED, EMBED);

  transpose_v<<<dim3(SEQ / 32, HDIM / 32, BATCH * NHEADS), 256, 0, stream>>>(Vw, VTw);

  attn_kernel<<<dim3(16, 16, 4), 256, 0, stream>>>(Qw, Kw, VTw, Aw);

  gemm128<1><<<dim3(1024 / 128, 8192 / 128), 256, 0, stream>>>(
      Aw, WTo, bob, (ushort*)d_out, nullptr, nullptr, flag, BATCH * SEQ, EMBED, EMBED);
}

// Round 5
// 288.565 us; speedup vs baseline: 1.1394x; 1.0223x over previous
//
#include <hip/hip_runtime.h>
#include <hip/hip_bf16.h>
#include <cstdint>
#include <cstddef>

#define BATCH  4
#define SEQ    2048
#define EMBED  1024
#define NHEADS 16
#define HDIM   64

typedef __attribute__((ext_vector_type(8))) short  short8;   // 8 x bf16 (4 VGPRs)
typedef __attribute__((ext_vector_type(4))) float  floatx4;  // MFMA C/D

#define MASK_NEG (-1.0e30f)   // finite "minus infinity": no inf-inf NaN paths
#define LOG2E    1.44269504f

__device__ __forceinline__ float bf2f(ushort u) {
  union { uint32_t i; float f; } v; v.i = ((uint32_t)u) << 16; return v.f;
}
__device__ __forceinline__ ushort f2bf(float f) {
  union { float f; uint32_t i; } v; v.f = f;
  uint32_t u = v.i;
  return (ushort)((u + 0x7fffu + ((u >> 16) & 1u)) >> 16);   // RNE
}
// packed RNE f32x2 -> bf16x2 (v_cvt_pk_bf16_f32 on gfx950)
__device__ __forceinline__ uint32_t f2bf_pk(float a, float b) {
  union { __hip_bfloat162 h; uint32_t u; } v;
  v.h = __float22bfloat162_rn(make_float2(a, b));
  return v.u;
}
// raw v_exp_f32 (2^x): guaranteed single instruction, denorm-flush is fine
// (underflowed P terms contribute nothing).
__device__ __forceinline__ float fast_exp2(float x) {
  float r;
  asm("v_exp_f32 %0, %1" : "=v"(r) : "v"(x));
  return r;
}
__device__ __forceinline__ floatx4 max4(floatx4 a, floatx4 b) {
  floatx4 r;
  r[0] = fmaxf(a[0], b[0]); r[1] = fmaxf(a[1], b[1]);
  r[2] = fmaxf(a[2], b[2]); r[3] = fmaxf(a[3], b[3]);
  return r;
}
// async global->LDS 16B/lane; LDS dst must be wave-uniform base + lane*16
__device__ __forceinline__ void gll16(const ushort* g, ushort* l) {
  __builtin_amdgcn_global_load_lds(
      (const __attribute__((address_space(1))) void*)g,
      (__attribute__((address_space(3))) void*)l, 16, 0, 0);
}

// ---------------------------------------------------------------------------
// Dtype detection (flag=1 bf16-packed, 0 fp32). Verified working since round 3.
// ---------------------------------------------------------------------------
__global__ __launch_bounds__(256) void detect_dtype(
    const uint32_t* __restrict__ x, int* __restrict__ flag) {
  __shared__ int sh[256];
  int tid = threadIdx.x;
  int c = 0;
#pragma unroll
  for (int i = 0; i < 16; i++) {
    uint32_t w = x[tid * 16 + i];
    uint32_t lo = w & 0xFFFFu;
    int e = (int)((lo >> 7) & 0xFF);
    if (lo == 0u || (e >= 100 && e <= 140)) c++;
  }
  sh[tid] = c;
  __syncthreads();
  if (tid == 0) {
    int s = 0;
    for (int i = 0; i < 256; i++) s += sh[i];
    *flag = (s >= 3500) ? 1 : 0;
  }
}

// vectorized x conversion: 4 elems/thread/step
__global__ __launch_bounds__(256) void cvt_bf16_v4(
    const void* __restrict__ in, ushort* __restrict__ out,
    const int* __restrict__ flag, int n4) {
  bool isbf = (*flag != 0);
  int stride = gridDim.x * 256;
  for (int i = blockIdx.x * 256 + threadIdx.x; i < n4; i += stride) {
    if (isbf) {
      ((uint2*)out)[i] = ((const uint2*)in)[i];
    } else {
      float4 f = ((const float4*)in)[i];
      uint2 o;
      o.x = f2bf_pk(f.x, f.y);
      o.y = f2bf_pk(f.z, f.w);
      ((uint2*)out)[i] = o;
    }
  }
}

// both biases in one launch: i<3072 -> bqb, else bob
__global__ __launch_bounds__(256) void cvt_biases(
    const void* __restrict__ bq, const void* __restrict__ bo,
    ushort* __restrict__ bqb, ushort* __restrict__ bob,
    const int* __restrict__ flag) {
  bool isbf = (*flag != 0);
  int i = blockIdx.x * 256 + threadIdx.x;
  if (i < 3 * EMBED) {
    bqb[i] = isbf ? ((const ushort*)bq)[i] : f2bf(((const float*)bq)[i]);
  } else {
    int j = i - 3 * EMBED;
    bob[j] = isbf ? ((const ushort*)bo)[j] : f2bf(((const float*)bo)[j]);
  }
}

__global__ __launch_bounds__(256) void transpose_cvt(
    const void* __restrict__ in, ushort* __restrict__ out,
    const int* __restrict__ flag, int R, int C) {
  bool isbf = (*flag != 0);
  __shared__ ushort tile[32][33];
  int bx = blockIdx.x * 32;
  int by = blockIdx.y * 32;
  int tx = threadIdx.x & 31, ty = threadIdx.x >> 5;
#pragma unroll
  for (int i = 0; i < 32; i += 8) {
    size_t idx = (size_t)(by + ty + i) * C + bx + tx;
    tile[ty + i][tx] = isbf ? ((const ushort*)in)[idx] : f2bf(((const float*)in)[idx]);
  }
  __syncthreads();
#pragma unroll
  for (int i = 0; i < 32; i += 8)
    out[(size_t)(bx + ty + i) * R + by + tx] = tile[tx][ty + i];
}

// ---------------------------------------------------------------------------
// Batched transpose: V (BH, S, D) bf16 -> VT (BH, D, S) bf16.
// ---------------------------------------------------------------------------
__global__ __launch_bounds__(256) void transpose_v(
    const ushort* __restrict__ in, ushort* __restrict__ out) {
  __shared__ ushort tile[32][33];
  int bh = blockIdx.z;
  int s0 = blockIdx.x * 32;
  int d0 = blockIdx.y * 32;
  int tx = threadIdx.x & 31, ty = threadIdx.x >> 5;
  const ushort* ip = in + (size_t)bh * SEQ * HDIM;
  ushort* op = out + (size_t)bh * SEQ * HDIM;
#pragma unroll
  for (int i = 0; i < 32; i += 8)
    tile[ty + i][tx] = ip[(size_t)(s0 + ty + i) * HDIM + d0 + tx];
  __syncthreads();
#pragma unroll
  for (int i = 0; i < 32; i += 8)
    op[(size_t)(d0 + ty + i) * SEQ + s0 + tx] = tile[tx][ty + i];
}

// ---------------------------------------------------------------------------
// GEMM v2: plain block mapping (XCD remap proved neutral in r4), BK=64,
// global_load_lds width-16 staging into XOR-chunk-swizzled unpadded LDS.
// ---------------------------------------------------------------------------
template <int EPI>
__global__ __launch_bounds__(256) void gemm128(
    const ushort* __restrict__ A, const ushort* __restrict__ BT,
    const ushort* __restrict__ bias,
    ushort* __restrict__ out0, ushort* __restrict__ out1, ushort* __restrict__ out2,
    const int* __restrict__ flag,
    int M, int N, int K) {
  __shared__ __align__(16) ushort Al[128 * 64];
  __shared__ __align__(16) ushort Bl[128 * 64];

  const int tid  = threadIdx.x;
  const int lane = tid & 63, wave = tid >> 6;
  const int quad = lane >> 4, l15 = lane & 15;
  const int wm = wave >> 1, wn = wave & 1;
  const int rowA0 = blockIdx.y * 128;
  const int colB0 = blockIdx.x * 128;

  floatx4 acc[4][4] = {};

  int srow[4], sc8[4];
#pragma unroll
  for (int j = 0; j < 4; j++) {
    int s = tid + j * 256;
    srow[j] = s >> 3;
    sc8[j] = ((s & 7) ^ (srow[j] & 7)) * 8;
  }

  for (int kk = 0; kk < K; kk += 64) {
    __syncthreads();
#pragma unroll
    for (int j = 0; j < 4; j++)
      gll16(&A[(size_t)(rowA0 + srow[j]) * K + kk + sc8[j]], &Al[(tid + j * 256) * 8]);
#pragma unroll
    for (int j = 0; j < 4; j++)
      gll16(&BT[(size_t)(colB0 + srow[j]) * K + kk + sc8[j]], &Bl[(tid + j * 256) * 8]);
    __syncthreads();

#pragma unroll
    for (int h = 0; h < 2; h++) {
      short8 af[4], bf[4];
#pragma unroll
      for (int mt = 0; mt < 4; mt++) {
        int row = wm * 64 + mt * 16 + l15;
        int pos = (quad + 4 * h) ^ (l15 & 7);
        af[mt] = *(const short8*)&Al[row * 64 + pos * 8];
      }
#pragma unroll
      for (int nt = 0; nt < 4; nt++) {
        int row = wn * 64 + nt * 16 + l15;
        int pos = (quad + 4 * h) ^ (l15 & 7);
        bf[nt] = *(const short8*)&Bl[row * 64 + pos * 8];
      }
#pragma unroll
      for (int mt = 0; mt < 4; mt++)
#pragma unroll
        for (int nt = 0; nt < 4; nt++)
          acc[mt][nt] = __builtin_amdgcn_mfma_f32_16x16x32_bf16(af[mt], bf[nt], acc[mt][nt], 0, 0, 0);
    }
  }

  const bool isbf = (EPI == 1) ? (*flag != 0) : true;

#pragma unroll
  for (int mt = 0; mt < 4; mt++)
#pragma unroll
    for (int nt = 0; nt < 4; nt++)
#pragma unroll
      for (int r = 0; r < 4; r++) {
        int row = rowA0 + wm * 64 + mt * 16 + quad * 4 + r;
        int col = colB0 + wn * 64 + nt * 16 + l15;
        float v = acc[mt][nt][r] + bf2f(bias[col]);
        if (EPI == 0) {
          int three = col >> 10, rem = col & 1023, h = rem >> 6, d = rem & 63;
          int b = row >> 11, s = row & 2047;
          ushort* dst = (three == 0) ? out0 : (three == 1) ? out1 : out2;
          dst[((size_t)(b * NHEADS + h) * SEQ + s) * HDIM + d] = f2bf(v);
        } else {
          if (isbf) out0[(size_t)row * N + col] = f2bf(v);
          else      ((float*)out0)[(size_t)row * N + col] = v;
        }
      }
}

// ---------------------------------------------------------------------------
// Flash attention v12: r3's DS-amortization WITHOUT r3's load-imbalance.
// 32 q-rows/wave (mf=2: K/V fragment reads shared across both halves ->
// DS per 16-row unit 240->144 cyc) + diagonal PAIRING restored (128-row
// q-tiles, pairs (p,15-p) -> uniform 36 tiles/block) + v11 DMA staging.
// Grid 8 pairs x 64 bh = 512 blocks = 2 blocks/CU (8 waves/CU); LDS 49152.
// Floors: DS ~35 us, VALU ~41 us (unchanged per-element softmax work).
// Rest unchanged: XOR swizzle, defer-max THR=8, fast_exp2, quad-partial li,
// peeled masked diagonal tiles, 1 barrier/iter, XCD bh-grouping.
// ---------------------------------------------------------------------------
__global__ __launch_bounds__(256, 2) void attn_kernel(
    const ushort* __restrict__ Q, const ushort* __restrict__ K,
    const ushort* __restrict__ VT, ushort* __restrict__ Oout) {
  __shared__ __align__(16) ushort Kl[2][64 * 64];   // [key][d], swizzled
  __shared__ __align__(16) ushort Vt[2][64 * 64];   // [d][key], swizzled
  __shared__ __align__(16) ushort Pl[4][32 * 64];   // per-wave [qrow][key], swizzled

  const int tid  = threadIdx.x;
  const int lane = tid & 63, wave = tid >> 6;
  const int quad = lane >> 4, l15 = lane & 15;

  // XCD-aware remap: 512 blocks; xcd = L%8 owns 8 consecutive bh (K/V
  // 8 x 512KB fits its 4 MiB L2); 8 diagonal pairs per bh.
  const int L   = blockIdx.x + 8 * blockIdx.y + 128 * blockIdx.z;  // 0..511
  const int xcd = L & 7;
  const int idx = L >> 3;                 // 0..63
  const int bh  = xcd * 8 + (idx >> 3);   // 0..63
  const int p   = idx & 7;                // diagonal pair index 0..7
  const int h   = bh & 15, b = bh >> 4;

  const ushort* Qp  = Q  + (size_t)bh * SEQ * HDIM;
  const ushort* Kp  = K  + (size_t)bh * SEQ * HDIM;
  const ushort* VTp = VT + (size_t)bh * SEQ * HDIM;  // [d][s]

  const float slope2 = exp2f(-0.5f * (float)(h + 1)) * LOG2E;
  const float c2 = 0.125f * LOG2E;

  // per-element ALiBi offsets within a tile: slope2 * (key - kb)
  floatx4 ab[4];
#pragma unroll
  for (int kct = 0; kct < 4; kct++)
#pragma unroll
    for (int r = 0; r < 4; r++)
      ab[kct][r] = slope2 * (float)(kct * 16 + quad * 4 + r);

  // DMA staging: thread covers (row = tid>>3, pos = tid&7) and (row+32, pos).
  // LDS dest linear: elem tid*8 (+2048 for second half). Source chunk
  // pre-swizzled: c = pos ^ (row&7); (row+32)&7 == row&7.
  const int sr0 = tid >> 3;
  const int scc = ((tid & 7) ^ (sr0 & 7)) * 8;        // source elem offset
  const int sxr = l15 & 7;                            // read-side swizzle

#define STAGE(KB, BUF)                                                        \
  do {                                                                        \
    gll16(&Kp[(size_t)((KB) + sr0) * HDIM + scc],       &Kl[BUF][tid * 8]);   \
    gll16(&Kp[(size_t)((KB) + sr0 + 32) * HDIM + scc],  &Kl[BUF][tid * 8 + 2048]); \
    gll16(&VTp[(size_t)sr0 * SEQ + (KB) + scc],         &Vt[BUF][tid * 8]);   \
    gll16(&VTp[(size_t)(sr0 + 32) * SEQ + (KB) + scc],  &Vt[BUF][tid * 8 + 2048]); \
  } while (0)

// one K/V tile for BOTH mf halves (shared K/V fragment reads).
// MASKED is a literal 0/1 at every expansion site.
#define ATTN_TILE(KB, CUR, MASKED)                                            \
  do {                                                                        \
    short8 kfa[4], kfb[4];                                                    \
    _Pragma("unroll")                                                         \
    for (int kct = 0; kct < 4; kct++) {                                       \
      const ushort* kr = &Kl[CUR][(kct * 16 + l15) * 64];                     \
      kfa[kct] = *(const short8*)&kr[(quad ^ sxr) * 8];                       \
      kfb[kct] = *(const short8*)&kr[((quad + 4) ^ sxr) * 8];                 \
    }                                                                         \
    _Pragma("unroll")                                                         \
    for (int mf = 0; mf < 2; mf++) {                                          \
      floatx4 w[4];                                                           \
      _Pragma("unroll")                                                       \
      for (int kct = 0; kct < 4; kct++) {                                     \
        floatx4 z = {};                                                       \
        z = __builtin_amdgcn_mfma_f32_16x16x32_bf16(kfa[kct], qf[mf][0], z, 0, 0, 0); \
        z = __builtin_amdgcn_mfma_f32_16x16x32_bf16(kfb[kct], qf[mf][1], z, 0, 0, 0); \
        w[kct] = z * c2 + ab[kct];                                            \
      }                                                                       \
      if (MASKED) {                                                           \
        const float qrel = qrowf[mf] - (float)(KB);                           \
        _Pragma("unroll")                                                     \
        for (int kct = 0; kct < 4; kct++)                                     \
          _Pragma("unroll")                                                   \
          for (int r = 0; r < 4; r++)                                         \
            if ((float)(kct * 16 + quad * 4 + r) > qrel) w[kct][r] = MASK_NEG;\
      }                                                                       \
      floatx4 wm4 = max4(max4(w[0], w[1]), max4(w[2], w[3]));                 \
      float mloc = fmaxf(fmaxf(wm4[0], wm4[1]), fmaxf(wm4[2], wm4[3]));       \
      mloc = fmaxf(mloc, __shfl_xor(mloc, 16, 64));                           \
      mloc = fmaxf(mloc, __shfl_xor(mloc, 32, 64));                           \
      const float bk = slope2 * (float)(KB);                                  \
      const float mlt = mloc + bk;                                            \
      const unsigned long long g = __ballot(mlt > m2s[mf] + 8.0f);            \
      float al = 1.0f;                                                        \
      if (g) {                                                                \
        float mn = fmaxf(m2s[mf], mlt);                                       \
        al = fast_exp2(m2s[mf] - mn);                                         \
        m2s[mf] = mn;                                                         \
      }                                                                       \
      const float mnb = m2s[mf] - bk;                                         \
      float rs = 0.f;                                                         \
      _Pragma("unroll")                                                       \
      for (int kct = 0; kct < 4; kct++) {                                     \
        float p0 = fast_exp2(w[kct][0] - mnb);                                \
        float p1 = fast_exp2(w[kct][1] - mnb);                                \
        float p2 = fast_exp2(w[kct][2] - mnb);                                \
        float p3 = fast_exp2(w[kct][3] - mnb);                                \
        rs += (p0 + p1) + (p2 + p3);                                          \
        uint2 pw;                                                             \
        pw.x = f2bf_pk(p0, p1);                                               \
        pw.y = f2bf_pk(p2, p3);                                               \
        *(uint2*)&Pl[wave][(mf * 16 + l15) * 64 +                             \
                           ((kct * 2 + (quad >> 1)) ^ sxr) * 8 +              \
                           (quad & 1) * 4] = pw;                              \
      }                                                                       \
      if (g) {                                                                \
        floatx4 alrv;                                                         \
        _Pragma("unroll")                                                     \
        for (int r = 0; r < 4; r++) alrv[r] = __shfl(al, quad * 4 + r, 16);   \
        _Pragma("unroll")                                                     \
        for (int ct = 0; ct < 4; ct++) o_acc[mf][ct] *= alrv;                 \
        lis[mf] = lis[mf] * al + rs;                                          \
      } else {                                                                \
        lis[mf] += rs;                                                        \
      }                                                                       \
    }                                                                         \
    _Pragma("unroll")                                                         \
    for (int ks = 0; ks < 2; ks++) {                                          \
      short8 vf[4];                                                           \
      _Pragma("unroll")                                                       \
      for (int ct = 0; ct < 4; ct++)                                          \
        vf[ct] = *(const short8*)&Vt[CUR][(ct * 16 + l15) * 64 +              \
                                          ((ks * 4 + quad) ^ sxr) * 8];       \
      _Pragma("unroll")                                                       \
      for (int mf = 0; mf < 2; mf++) {                                        \
        short8 pf = *(const short8*)&Pl[wave][(mf * 16 + l15) * 64 +          \
                                              ((ks * 4 + quad) ^ sxr) * 8];   \
        _Pragma("unroll")                                                     \
        for (int ct = 0; ct < 4; ct++)                                        \
          o_acc[mf][ct] = __builtin_amdgcn_mfma_f32_16x16x32_bf16(            \
              pf, vf[ct], o_acc[mf][ct], 0, 0, 0);                            \
      }                                                                       \
    }                                                                         \
  } while (0)

  for (int qsel = 0; qsel < 2; qsel++) {
    const int qt  = qsel ? (15 - p) : p;      // 0..15 (128-row q-tiles)
    const int wq0 = qt * 128 + wave * 32;

    short8 qf[2][2];
#pragma unroll
    for (int mf = 0; mf < 2; mf++) {
      const ushort* qr = &Qp[(size_t)(wq0 + mf * 16 + l15) * HDIM];
      qf[mf][0] = *(const short8*)&qr[quad * 8];
      qf[mf][1] = *(const short8*)&qr[32 + quad * 8];
    }

    float m2s[2] = {MASK_NEG, MASK_NEG}, lis[2] = {0.f, 0.f};  // quad-partial li
    float qrowf[2];
#pragma unroll
    for (int mf = 0; mf < 2; mf++) qrowf[mf] = (float)(wq0 + mf * 16 + l15);
    floatx4 o_acc[2][4] = {};

    // prologue: barrier (prev qsel's readers of buf0), then DMA tile 0
    __syncthreads();
    STAGE(0, 0);
    __syncthreads();   // drains own vmcnt, then barrier -> buf0 ready

    // tiles 0 .. 2qt+1; tiles < 2qt are unmasked for all waves
    const int nfull = 2 * qt;
    for (int kt = 0; kt < nfull; kt++) {
      const int cur = kt & 1;
      STAGE((kt + 1) * 64, cur ^ 1);   // async DMA next tile
      ATTN_TILE(kt * 64, cur, 0);
      __syncthreads();                 // drain DMA + make it visible
    }

    // tile 2qt: diagonal for waves 0,1; mask is never-true for waves 2,3.
    // Prefetch tile 2qt+1 (needed by waves 2,3).
    {
      const int cur = nfull & 1;
      STAGE((nfull + 1) * 64, cur ^ 1);
      ATTN_TILE(nfull * 64, cur, 1);
      __syncthreads();
    }

    // tile 2qt+1: diagonal for waves 2,3; fully masked (zero) for waves 0,1.
    // No trailing barrier (next qsel's prologue barrier covers buffer reuse).
    if (wave & 2) {
      ATTN_TILE((nfull + 1) * 64, (nfull + 1) & 1, 1);
    }

    // epilogue: O rows q = wq0+mf*16+quad*4+r, cols d = ct*16+l15
#pragma unroll
    for (int mf = 0; mf < 2; mf++) {
      float lif = lis[mf] + __shfl_xor(lis[mf], 16, 64);
      lif += __shfl_xor(lif, 32, 64);
      float inv = 1.0f / fmaxf(lif, 1e-20f);
      float invr[4];
#pragma unroll
      for (int r = 0; r < 4; r++) invr[r] = __shfl(inv, quad * 4 + r, 16);
#pragma unroll
      for (int ct = 0; ct < 4; ct++)
#pragma unroll
        for (int r = 0; r < 4; r++) {
          int q = wq0 + mf * 16 + quad * 4 + r;
          float v = o_acc[mf][ct][r] * invr[r];
          Oout[(size_t)(b * SEQ + q) * EMBED + h * HDIM + ct * 16 + l15] = f2bf(v);
        }
    }
  }
#undef ATTN_TILE
#undef STAGE
}

// ---------------------------------------------------------------------------
// ws layout (bytes):
//   flag @ 0          (1024)
//   xb   @ 1024       16777216
//   WTq  @ 16778240    6291456
//   WTo  @ 23069696    2097152
//   bqb  @ 25166848       6144
//   bob  @ 25172992       2048
//   Kw   @ 25175040   16777216
//   Vw   @ 41952256   16777216   (dead after transpose_v -> reused as Aw)
//   VT   @ 58729472   16777216   -> end 75506688
//   Qw   @ 75506688 if ws fits, else Q lives in d_out.
// ---------------------------------------------------------------------------
extern "C" void kernel_launch(void* const* d_in, const int* in_sizes, int n_in,
                              void* d_out, int out_size, void* d_ws, size_t ws_size,
                              hipStream_t stream) {
  const void* x     = d_in[0];
  const void* W_qkv = d_in[2];
  const void* b_qkv = d_in[3];
  const void* W_out = d_in[4];
  const void* b_out = d_in[5];

  char* ws = (char*)d_ws;
  int*    flag = (int*)(ws + 0);
  ushort* xb   = (ushort*)(ws + 1024);
  ushort* WTq  = (ushort*)(ws + 16778240);
  ushort* WTo  = (ushort*)(ws + 23069696);
  ushort* bqb  = (ushort*)(ws + 25166848);
  ushort* bob  = (ushort*)(ws + 25172992);
  ushort* Kw   = (ushort*)(ws + 25175040);
  ushort* Vw   = (ushort*)(ws + 41952256);
  ushort* VTw  = (ushort*)(ws + 58729472);
  ushort* Aw   = Vw;   // Vw dead after transpose_v
  ushort* Qw   = (ws_size >= (size_t)75506688 + 16777216)
                   ? (ushort*)(ws + 75506688)
                   : (ushort*)d_out;   // d_out as scratch: dead until final GEMM

  detect_dtype<<<1, 256, 0, stream>>>((const uint32_t*)x, flag);

  cvt_bf16_v4<<<2048, 256, 0, stream>>>(x, xb, flag, BATCH * SEQ * EMBED / 4);
  cvt_biases<<<16, 256, 0, stream>>>(b_qkv, b_out, bqb, bob, flag);

  transpose_cvt<<<dim3(3072 / 32, 1024 / 32), 256, 0, stream>>>(W_qkv, WTq, flag, 1024, 3072);
  transpose_cvt<<<dim3(1024 / 32, 1024 / 32), 256, 0, stream>>>(W_out, WTo, flag, 1024, 1024);

  gemm128<0><<<dim3(3072 / 128, 8192 / 128), 256, 0, stream>>>(
      xb, WTq, bqb, Qw, Kw, Vw, flag, BATCH * SEQ, 3 * EMBED, EMBED);

  transpose_v<<<dim3(SEQ / 32, HDIM / 32, BATCH * NHEADS), 256, 0, stream>>>(Vw, VTw);

  attn_kernel<<<dim3(8, 16, 4), 256, 0, stream>>>(Qw, Kw, VTw, Aw);

  gemm128<1><<<dim3(1024 / 128, 8192 / 128), 256, 0, stream>>>(
      Aw, WTo, bob, (ushort*)d_out, nullptr, nullptr, flag, BATCH * SEQ, EMBED, EMBED);
}